// Round 10
// baseline (52.528 us; speedup 1.0000x reference)
//
#include <hip/hip_runtime.h>

// NovelKQRAttention — algebraically collapsed, 3-kernel chain.
// energy = a[...,q,None] + b[...,None,k]; softmax over k => a cancels,
// attn = softmax_k(b) independent of q => deform-conv path is dead,
// attention output constant over spatial dims.
//
//   K1 k_bpart : partial b[n,h,k] per 72-ch chunk (kb-slice inline), 64 blocks;
//                also writes compact xkv[n,c,k]; block(0,0,0) zeroes ov.
//   K2 k_swxov : per-block: 8-chunk-sum -> LDS, softmax in LDS (redundant,
//                deterministic per value), wx for 4 channels (1/wave) from
//                compact xkv (float4), then partial ov via atomicAdd.
//                grid (144,2) = 288 blocks — wide.
//   K3 k_pofinal: po = proj_w[o,:].ov[n,:] + proj_b; out row = gamma*po + x row
//                (block per (n,o) row, 1152 blocks — streams 38 MB)

#define CCH 576
#define NH 9
#define HW 4096   // 64*64
#define KHW 1024  // 32*32
#define W 64
#define CHN 8     // channel chunks
#define CPC 72    // channels per chunk

// ws float offsets
#define WS_XKV   0                           // 2*576*1024 = 1179648
#define WS_BPART 1179648                     // 8*2*9*1024 = 147456 (layout [ch][n][h][k])
#define WS_OV    (1179648 + 147456)          // 2*576 = 1152

// grid (4 kblk, 2 n, 8 chunk), block 256.
__global__ void k_bpart(const float* __restrict__ x, const float* __restrict__ key_w,
                        const float* __restrict__ appr_bias, float* __restrict__ bpart,
                        float* __restrict__ xkv, float* __restrict__ ov) {
    int k  = blockIdx.x * 256 + threadIdx.x;   // 0..1023
    int n  = blockIdx.y;
    int ch = blockIdx.z;
    int c0 = ch * CPC;

    // zero the atomic ov accumulator for K2 (any single block; runs before K2)
    if (blockIdx.x == 0 && blockIdx.y == 0 && blockIdx.z == 0)
        for (int i = threadIdx.x; i < 2 * CCH; i += 256) ov[i] = 0.f;

    __shared__ float ab[CCH];
    __shared__ float kbs[NH][CPC];
    for (int i = threadIdx.x; i < CCH; i += 256) ab[i] = appr_bias[i];
    __syncthreads();
    for (int t = threadIdx.x; t < NH * CPC; t += 256) {
        int h = t / CPC, cl = t % CPC;
        float s = 0.f;
        #pragma unroll 8
        for (int e = 0; e < 64; ++e)
            s += ab[h * 64 + e] * key_w[(size_t)(h * 64 + e) * CCH + c0 + cl];
        kbs[h][cl] = s;
    }
    __syncthreads();

    int ky = k >> 5, kx = k & 31;
    const float* xb = x + (size_t)n * CCH * HW + (size_t)c0 * HW + (size_t)(ky * 2) * W + kx * 2;
    float acc[NH];
    #pragma unroll
    for (int h = 0; h < NH; ++h) acc[h] = 0.f;
    #pragma unroll 8
    for (int cl = 0; cl < CPC; ++cl) {
        float xv = xb[(size_t)cl * HW];
        xkv[((size_t)n * CCH + c0 + cl) * KHW + k] = xv;   // compact x_kv
        #pragma unroll
        for (int h = 0; h < NH; ++h) acc[h] += kbs[h][cl] * xv;
    }
    #pragma unroll
    for (int h = 0; h < NH; ++h)
        bpart[(((size_t)ch * 2 + n) * NH + h) * KHW + k] = acc[h];
}

// grid (144, 2 n), block 256 (4 waves).
// A: sum 8 bpart chunks into LDS sm[9][1024] (float4; 294 KB/block, L2/L3).
// B: per-wave softmax of disjoint head rows (identical in every block).
// C: wave wv: channel c = bid.x*4+wv; wx[h] = sum_k p[h,k]*xkv[c,k] (float4).
// D: partial ov: ov[n,o] += sum_{j<4} value_w[o,c0+j]*wx[h(o),c0+j] (atomic).
__global__ void k_swxov(const float* __restrict__ xkv, const float* __restrict__ bpart,
                        const float* __restrict__ value_w, float* __restrict__ ov) {
    int n = blockIdx.y;
    int tid = threadIdx.x;
    int wv = tid >> 6, ln = tid & 63;
    __shared__ float sm[NH * KHW];   // 36 KB
    __shared__ float wxs[4][NH];

    // A: chunk-sum (element (h,k) of chunk ch at bpart[((ch*2+n)*NH+h)*KHW+k])
    const float4* bp4 = (const float4*)bpart;
    float4* sm4 = (float4*)sm;
    for (int i = tid; i < NH * KHW / 4; i += 256) {
        float4 v = make_float4(0.f, 0.f, 0.f, 0.f);
        #pragma unroll
        for (int ch = 0; ch < CHN; ++ch) {
            float4 b = bp4[(size_t)(ch * 2 + n) * (NH * KHW / 4) + i];
            v.x += b.x; v.y += b.y; v.z += b.z; v.w += b.w;
        }
        sm4[i] = v;
    }
    __syncthreads();

    // B: softmax per head-row (waves own disjoint rows; deterministic)
    for (int h = wv; h < NH; h += 4) {
        float* row = sm + h * KHW;
        float m = -1e30f;
        #pragma unroll
        for (int j = 0; j < 16; ++j) m = fmaxf(m, row[ln + 64 * j]);
        #pragma unroll
        for (int off = 32; off >= 1; off >>= 1) m = fmaxf(m, __shfl_xor(m, off, 64));
        float s = 0.f;
        #pragma unroll
        for (int j = 0; j < 16; ++j) {
            float e = __expf(row[ln + 64 * j] - m);
            row[ln + 64 * j] = e;
            s += e;
        }
        #pragma unroll
        for (int off = 32; off >= 1; off >>= 1) s += __shfl_xor(s, off, 64);
        float inv = 1.f / s;
        #pragma unroll
        for (int j = 0; j < 16; ++j) row[ln + 64 * j] *= inv;
    }
    __syncthreads();

    // C: wx for this wave's channel
    int c = blockIdx.x * 4 + wv;   // 0..575
    const float4* xr = (const float4*)(xkv + ((size_t)n * CCH + c) * KHW);
    float acc[NH];
    #pragma unroll
    for (int h = 0; h < NH; ++h) acc[h] = 0.f;
    #pragma unroll
    for (int j = 0; j < 4; ++j) {
        float4 xv = xr[ln + 64 * j];
        #pragma unroll
        for (int h = 0; h < NH; ++h) {
            float4 pv = ((const float4*)(sm + h * KHW))[ln + 64 * j];
            acc[h] += pv.x * xv.x + pv.y * xv.y + pv.z * xv.z + pv.w * xv.w;
        }
    }
    #pragma unroll
    for (int h = 0; h < NH; ++h) {
        float v = acc[h];
        #pragma unroll
        for (int off = 32; off >= 1; off >>= 1) v += __shfl_xor(v, off, 64);
        if (ln == 0) wxs[wv][h] = v;
    }
    __syncthreads();

    // D: partial ov over this block's 4 channels
    int c0 = blockIdx.x * 4;
    for (int o = tid; o < CCH; o += 256) {
        int h = o >> 6;
        float4 vw4 = *(const float4*)(value_w + (size_t)o * CCH + c0);
        float val = vw4.x * wxs[0][h] + vw4.y * wxs[1][h]
                  + vw4.z * wxs[2][h] + vw4.w * wxs[3][h];
        atomicAdd(&ov[n * CCH + o], val);
    }
}

// grid 1152 (= 2*576, one block per (n,o) row), block 256.
// Block-wide dot(proj_w[o,:], ov[n,:]) then stream out row = x row + base.
__global__ void k_pofinal(const float* __restrict__ proj_w, const float* __restrict__ proj_b,
                          const float* __restrict__ ov, const float* __restrict__ x,
                          const float* __restrict__ gamma, float* __restrict__ out) {
    int b = blockIdx.x;
    int n = b / CCH, o = b % CCH;
    int t = threadIdx.x;
    int wv = t >> 6, ln = t & 63;
    __shared__ float pr[4];

    const float* pw  = proj_w + (size_t)o * CCH;
    const float* ovr = ov + n * CCH;
    float acc = pw[t] * ovr[t] + pw[t + 256] * ovr[t + 256];
    if (t < 64) acc += pw[t + 512] * ovr[t + 512];
    #pragma unroll
    for (int off = 32; off >= 1; off >>= 1)
        acc += __shfl_xor(acc, off, 64);
    if (ln == 0) pr[wv] = acc;
    __syncthreads();
    float base = gamma[0] * ((pr[0] + pr[1] + pr[2] + pr[3]) + proj_b[o]);

    const float4* x4 = (const float4*)(x + ((size_t)n * CCH + o) * HW);
    float4* o4 = (float4*)(out + ((size_t)n * CCH + o) * HW);
    #pragma unroll
    for (int j = 0; j < 4; ++j) {
        int idx = t + 256 * j;           // 1024 float4 per row
        float4 v = x4[idx];
        v.x += base; v.y += base; v.z += base; v.w += base;
        o4[idx] = v;
    }
}

extern "C" void kernel_launch(void* const* d_in, const int* in_sizes, int n_in,
                              void* d_out, int out_size, void* d_ws, size_t ws_size,
                              hipStream_t stream) {
    const float* x         = (const float*)d_in[0];
    const float* key_w     = (const float*)d_in[1];
    // d_in[2] offset_w, d_in[3] dconv_w, d_in[8] appr_bias_q: dead path (a cancels in softmax)
    const float* value_w   = (const float*)d_in[4];
    const float* proj_w    = (const float*)d_in[5];
    const float* proj_b    = (const float*)d_in[6];
    const float* appr_bias = (const float*)d_in[7];
    const float* gamma     = (const float*)d_in[9];
    float* out = (float*)d_out;

    float* ws    = (float*)d_ws;
    float* xkv   = ws + WS_XKV;
    float* bpart = ws + WS_BPART;
    float* ov    = ws + WS_OV;

    k_bpart  <<<dim3(4, 2, CHN), 256, 0, stream>>>(x, key_w, appr_bias, bpart, xkv, ov);
    k_swxov  <<<dim3(144, 2), 256, 0, stream>>>(xkv, bpart, value_w, ov);
    k_pofinal<<<1152, 256, 0, stream>>>(proj_w, proj_b, ov, x, gamma, out);
}

// Round 11
// 43.710 us; speedup vs baseline: 1.2017x; 1.2017x over previous
//
#include <hip/hip_runtime.h>

// NovelKQRAttention — algebraically collapsed, 4-kernel chain.
// energy = a[...,q,None] + b[...,None,k]; softmax over k => a cancels,
// attn = softmax_k(b) independent of q => deform-conv path is dead,
// attention output constant over spatial dims.
//
//   K1 k_bpart  : partial b[n,h,k] per 36-ch chunk (kb-slice inline), 128 blocks;
//                 also writes compact xkv[n,c,k]
//   K2 k_softmax: sum 16 chunks + softmax over k=1024 -> p (18 blocks); zeroes ov
//   K3 k_wxov   : wx[h] per channel from compact xkv (float4) + partial-ov
//                 atomicAdd tail (R10-proven), 288 blocks
//   K4 k_pofinal: po = proj_w[o,:].ov[n,:] + proj_b; out row = gamma*po + x row
//                 (block per (n,o) row, 1152 blocks — streams 38 MB)

#define CCH 576
#define NH 9
#define HW 4096   // 64*64
#define KHW 1024  // 32*32
#define W 64
#define CHN 16    // channel chunks
#define CPC 36    // channels per chunk

// ws float offsets
#define WS_XKV   0                           // 2*576*1024 = 1179648
#define WS_BPART 1179648                     // 16*2*9*1024 = 294912 (layout [n][ch][h][k])
#define WS_P     (1179648 + 294912)          // 2*9*1024 = 18432
#define WS_OV    (1179648 + 294912 + 18432)  // 2*576 = 1152

// grid (4 kblk, 2 n, 16 chunk), block 256.
__global__ void k_bpart(const float* __restrict__ x, const float* __restrict__ key_w,
                        const float* __restrict__ appr_bias, float* __restrict__ bpart,
                        float* __restrict__ xkv) {
    int k  = blockIdx.x * 256 + threadIdx.x;   // 0..1023
    int n  = blockIdx.y;
    int ch = blockIdx.z;
    int c0 = ch * CPC;

    __shared__ float ab[CCH];
    __shared__ float kbs[NH][CPC];
    for (int i = threadIdx.x; i < CCH; i += 256) ab[i] = appr_bias[i];
    __syncthreads();
    for (int t = threadIdx.x; t < NH * CPC; t += 256) {
        int h = t / CPC, cl = t % CPC;
        float s = 0.f;
        #pragma unroll 8
        for (int e = 0; e < 64; ++e)
            s += ab[h * 64 + e] * key_w[(size_t)(h * 64 + e) * CCH + c0 + cl];
        kbs[h][cl] = s;
    }
    __syncthreads();

    int ky = k >> 5, kx = k & 31;
    const float* xb = x + (size_t)n * CCH * HW + (size_t)c0 * HW + (size_t)(ky * 2) * W + kx * 2;
    float acc[NH];
    #pragma unroll
    for (int h = 0; h < NH; ++h) acc[h] = 0.f;
    for (int cl = 0; cl < CPC; ++cl) {
        float xv = xb[(size_t)cl * HW];
        xkv[((size_t)n * CCH + c0 + cl) * KHW + k] = xv;   // compact x_kv
        #pragma unroll
        for (int h = 0; h < NH; ++h) acc[h] += kbs[h][cl] * xv;
    }
    #pragma unroll
    for (int h = 0; h < NH; ++h)
        bpart[(((size_t)n * CHN + ch) * NH + h) * KHW + k] = acc[h];
}

// grid 18 (= n*9), block 256. Sum 16 chunks, softmax over k=1024, write p.
// Block 0 also zeroes the ov atomic accumulator (runs strictly before k_wxov).
__global__ void k_softmax(const float* __restrict__ bpart, float* __restrict__ p,
                          float* __restrict__ ov) {
    if (blockIdx.x == 0)
        for (int i = threadIdx.x; i < 2 * CCH; i += 256) ov[i] = 0.f;
    int nh = blockIdx.x;
    int n = nh / NH, h = nh % NH;
    int tid = threadIdx.x;
    int wave = tid >> 6, lane = tid & 63;
    float s[4];
    #pragma unroll
    for (int j = 0; j < 4; ++j) {
        int k = tid + j * 256;
        float v = 0.f;
        #pragma unroll
        for (int ch = 0; ch < CHN; ++ch)
            v += bpart[(((size_t)n * CHN + ch) * NH + h) * KHW + k];
        s[j] = v;
    }
    float m = fmaxf(fmaxf(s[0], s[1]), fmaxf(s[2], s[3]));
    #pragma unroll
    for (int off = 32; off >= 1; off >>= 1)
        m = fmaxf(m, __shfl_xor(m, off, 64));
    __shared__ float redm[4];
    if (lane == 0) redm[wave] = m;
    __syncthreads();
    m = fmaxf(fmaxf(redm[0], redm[1]), fmaxf(redm[2], redm[3]));
    float e[4], lsum = 0.f;
    #pragma unroll
    for (int j = 0; j < 4; ++j) { e[j] = __expf(s[j] - m); lsum += e[j]; }
    #pragma unroll
    for (int off = 32; off >= 1; off >>= 1)
        lsum += __shfl_xor(lsum, off, 64);
    __shared__ float reds[4];
    if (lane == 0) reds[wave] = lsum;
    __syncthreads();
    float inv = 1.f / (reds[0] + reds[1] + reds[2] + reds[3]);
    #pragma unroll
    for (int j = 0; j < 4; ++j)
        p[(size_t)nh * KHW + tid + j * 256] = e[j] * inv;
}

// grid (144 c-tiles, 2 n), block 256 (4 waves). Wave = 1 channel (float4 reads),
// then partial-ov atomicAdd tail over this block's 4 channels.
__global__ void k_wxov(const float* __restrict__ xkv, const float* __restrict__ p,
                       const float* __restrict__ value_w, float* __restrict__ ov) {
    int n = blockIdx.y;
    int tid = threadIdx.x;
    int wv = tid >> 6, ln = tid & 63;
    __shared__ float ps[NH * KHW];   // 36 KB
    __shared__ float wxs[4][NH];
    const float4* p4 = (const float4*)(p + (size_t)n * NH * KHW);
    float4* ps4 = (float4*)ps;
    for (int i = tid; i < NH * KHW / 4; i += 256) ps4[i] = p4[i];
    __syncthreads();

    int c = blockIdx.x * 4 + wv;   // 0..575
    const float4* xr = (const float4*)(xkv + ((size_t)n * CCH + c) * KHW);
    float acc[NH];
    #pragma unroll
    for (int h = 0; h < NH; ++h) acc[h] = 0.f;
    #pragma unroll
    for (int j = 0; j < 4; ++j) {
        float4 xv = xr[ln + 64 * j];
        #pragma unroll
        for (int h = 0; h < NH; ++h) {
            float4 pv = ((const float4*)(ps + h * KHW))[ln + 64 * j];
            acc[h] += pv.x * xv.x + pv.y * xv.y + pv.z * xv.z + pv.w * xv.w;
        }
    }
    #pragma unroll
    for (int h = 0; h < NH; ++h) {
        float v = acc[h];
        #pragma unroll
        for (int off = 32; off >= 1; off >>= 1) v += __shfl_xor(v, off, 64);
        if (ln == 0) wxs[wv][h] = v;
    }
    __syncthreads();

    // partial ov over this block's 4 channels (R10-proven tail)
    int c0 = blockIdx.x * 4;
    for (int o = tid; o < CCH; o += 256) {
        int h = o >> 6;
        float4 vw4 = *(const float4*)(value_w + (size_t)o * CCH + c0);
        float val = vw4.x * wxs[0][h] + vw4.y * wxs[1][h]
                  + vw4.z * wxs[2][h] + vw4.w * wxs[3][h];
        atomicAdd(&ov[n * CCH + o], val);
    }
}

// grid 1152 (= 2*576, one block per (n,o) row), block 256.
// Block-wide dot(proj_w[o,:], ov[n,:]) then stream out row = x row + base.
__global__ void k_pofinal(const float* __restrict__ proj_w, const float* __restrict__ proj_b,
                          const float* __restrict__ ov, const float* __restrict__ x,
                          const float* __restrict__ gamma, float* __restrict__ out) {
    int b = blockIdx.x;
    int n = b / CCH, o = b % CCH;
    int t = threadIdx.x;
    int wv = t >> 6, ln = t & 63;
    __shared__ float pr[4];

    const float* pw  = proj_w + (size_t)o * CCH;
    const float* ovr = ov + n * CCH;
    float acc = pw[t] * ovr[t] + pw[t + 256] * ovr[t + 256];
    if (t < 64) acc += pw[t + 512] * ovr[t + 512];
    #pragma unroll
    for (int off = 32; off >= 1; off >>= 1)
        acc += __shfl_xor(acc, off, 64);
    if (ln == 0) pr[wv] = acc;
    __syncthreads();
    float base = gamma[0] * ((pr[0] + pr[1] + pr[2] + pr[3]) + proj_b[o]);

    const float4* x4 = (const float4*)(x + ((size_t)n * CCH + o) * HW);
    float4* o4 = (float4*)(out + ((size_t)n * CCH + o) * HW);
    #pragma unroll
    for (int j = 0; j < 4; ++j) {
        int idx = t + 256 * j;           // 1024 float4 per row
        float4 v = x4[idx];
        v.x += base; v.y += base; v.z += base; v.w += base;
        o4[idx] = v;
    }
}

extern "C" void kernel_launch(void* const* d_in, const int* in_sizes, int n_in,
                              void* d_out, int out_size, void* d_ws, size_t ws_size,
                              hipStream_t stream) {
    const float* x         = (const float*)d_in[0];
    const float* key_w     = (const float*)d_in[1];
    // d_in[2] offset_w, d_in[3] dconv_w, d_in[8] appr_bias_q: dead path (a cancels in softmax)
    const float* value_w   = (const float*)d_in[4];
    const float* proj_w    = (const float*)d_in[5];
    const float* proj_b    = (const float*)d_in[6];
    const float* appr_bias = (const float*)d_in[7];
    const float* gamma     = (const float*)d_in[9];
    float* out = (float*)d_out;

    float* ws    = (float*)d_ws;
    float* xkv   = ws + WS_XKV;
    float* bpart = ws + WS_BPART;
    float* p     = ws + WS_P;
    float* ov    = ws + WS_OV;

    k_bpart  <<<dim3(4, 2, CHN), 256, 0, stream>>>(x, key_w, appr_bias, bpart, xkv);
    k_softmax<<<18, 256, 0, stream>>>(bpart, p, ov);
    k_wxov   <<<dim3(144, 2), 256, 0, stream>>>(xkv, p, value_w, ov);
    k_pofinal<<<1152, 256, 0, stream>>>(proj_w, proj_b, ov, x, gamma, out);
}